// Round 14
// baseline (108.094 us; speedup 1.0000x reference)
//
#include <hip/hip_runtime.h>
#include <math.h>

#define B  32
#define P  128
#define L  19
#define H  256
#define SLOPE 0.2f
#define PL (P*L)          /* 2432 */
#define LH (L*H)          /* 4864 */
#define PLH (P*L*H)
#define NBLK (B*L)        /* 608 */

#define ABW2 136          /* Ab row stride (u16); 272 B = 17*16 (b128-aligned) */

typedef __attribute__((ext_vector_type(8))) short bf16x8;
typedef __attribute__((ext_vector_type(4))) float f32x4;
typedef __attribute__((ext_vector_type(4))) unsigned uint32x4;

__device__ inline unsigned short f32_to_bf16(float x) {
    unsigned u = __builtin_bit_cast(unsigned, x);
    unsigned r = (u + 0x7fffu + ((u >> 16) & 1u)) >> 16;
    return (unsigned short)r;
}

// ---------------------------------------------------------------------------
// prep: blocks [0, B*P): pack adj>0 into bits[b][l][i][jw] (coalesced reads).
//       block B*P: sniff mask layout + compute u1/u2.
// ---------------------------------------------------------------------------
__global__ __launch_bounds__(256) void prep(
    const float* __restrict__ adj,
    const unsigned char* __restrict__ m,
    const float* __restrict__ W1,
    const float* __restrict__ W2,
    unsigned* __restrict__ bits,
    int* __restrict__ flag,
    float* __restrict__ u)
{
    int blk = blockIdx.x;
    if (blk < B*P) {
        __shared__ unsigned char f[PL];
        int b = blk >> 7, i = blk & 127;
        const float4* row = (const float4*)(adj + (size_t)blk * PL);
        for (int q = threadIdx.x; q < PL/4; q += 256) {
            float4 v = row[q];
            f[q*4]   = v.x > 0.f;
            f[q*4+1] = v.y > 0.f;
            f[q*4+2] = v.z > 0.f;
            f[q*4+3] = v.w > 0.f;
        }
        __syncthreads();
        int t = threadIdx.x;
        if (t < 76) {
            int l = t >> 2, jw = t & 3;
            unsigned wv = 0;
            #pragma unroll
            for (int k = 0; k < 32; ++k)
                wv |= (unsigned)f[(jw*32 + k)*L + l] << k;
            bits[(((size_t)b*L + l)*P + i)*4 + jw] = wv;
        }
    } else {
        __shared__ int s;
        if (threadIdx.x == 0) s = 0;
        __syncthreads();
        int acc = 0;
        for (int k = threadIdx.x; k < 1024; k += 256)
            acc |= m[4*k+1] | m[4*k+2] | m[4*k+3];
        if (acc) atomicOr(&s, 1);
        __syncthreads();
        if (threadIdx.x == 0) flag[0] = s;   // 1 => byte mask, 0 => int32 mask
        int h = threadIdx.x;
        float s1 = 0.f, s2 = 0.f;
        for (int a = 0; a < 128; ++a) {
            float wv = W1[a*H + h];
            s1 += wv * W2[a];
            s2 += wv * W2[128 + a];
        }
        u[h]     = s1;
        u[H + h] = s2;
    }
}

// ---------------------------------------------------------------------------
// gat_main: block = (b, l), 512 threads (8 waves), 608 blocks, 2 blocks/CU.
// SINGLE-PASS structure (replaces R10-13's gather/double-buffer pipeline):
//  P0 : ballot; row_map = [compacted unmasked | masked] (both prefix sums);
//       u, bitw -> LDS.
//  P1 : per row-group g (4 thr): ONE coalesced read of agents row row_map[g]
//       computes e1/e2 AND stages the row bf16-transposed into Ab[h][g]
//       (64 ds_write_b16/thread, 2-way banks = free); pad columns [M,Kn*32)
//       written as zeros (0*garbage would NaN the MFMA otherwise).
//  P2 : softmax, chunk-of-8 mapping: thread (i, c) produces W[i][ks*32+c*8
//       .. +8] = exactly one A-fragment word-set; closed-form row max
//       (monotone leaky); 1/sum deferred to epilogue. Fragments + invs reach
//       the MFMA lanes via __shfl (src = (lane&15)*4 + (lane>>4)) — W never
//       touches LDS.
//  P3 : MFMA + sigmoid epilogue, NO barriers: 16 h-tiles x Kn mfma_16x16x32.
// Barriers: 3 total (vs ~10 in R12). LDS 75.3 KB -> 2 blocks/CU.
// ---------------------------------------------------------------------------
__global__ __launch_bounds__(512, 4) void gat_main(
    const float* __restrict__ A,
    const unsigned* __restrict__ bits,
    const void*  __restrict__ maskp,
    const int*   __restrict__ flagp,
    const float* __restrict__ u,
    float* __restrict__ out)
{
    __shared__ __align__(16) unsigned short Ab[256*ABW2]; // 69632 B [h][jj]
    __shared__ __align__(16) float u_lds[2*H];            //  2048 B
    __shared__ unsigned bitw[P*4];                        //  2048 B
    __shared__ float e1f[P];      // e1 by ORIGINAL row index
    __shared__ float e2c[P];      // e2 by compact jj
    __shared__ int   row_map[P];  // [joff(M) | masked rows]
    __shared__ int   cnt[2];

    // XCD swizzle: same-b blocks land on one XCD (agents[b] ~2.4MB in L2)
    int w   = blockIdx.x;
    int xcd = w & 7;
    int q   = w >> 3;            // 0..75
    int l   = q % 19;
    int bg  = q / 19;            // 0..3
    int b   = bg*8 + xcd;
    int tid = threadIdx.x;

    // ---- P0: ballot + row_map (keep-compact | masked-compact), u, bitw
    int flag = flagp[0];
    int keep = 0;
    if (tid < P) {
        int mv = flag ? (((const unsigned char*)maskp)[b*P + tid] != 0)
                      : (((const int*)maskp)[b*P + tid] != 0);
        keep = !mv;
    }
    unsigned long long bal = __ballot(keep);
    if (tid == 0)  cnt[0] = (int)__popcll(bal);
    if (tid == 64) cnt[1] = (int)__popcll(bal);
    u_lds[tid] = u[tid];
    bitw[tid]  = bits[(((size_t)b*L + l)*P)*4 + tid];
    __syncthreads();                               // S1
    int M  = cnt[0] + cnt[1];
    int Kn = (M + 31) >> 5;
    int KT = Kn * 32;
    if (tid < P) {
        int lane = tid & 63;
        unsigned long long below = (1ull << lane) - 1ull;
        if (keep) {
            int pos = (int)__popcll(bal & below) + (tid >= 64 ? cnt[0] : 0);
            row_map[pos] = tid;
        } else {
            int pos = (int)__popcll(~bal & below) + (tid >= 64 ? 64 - cnt[0] : 0);
            row_map[M + pos] = tid;
        }
    }
    __syncthreads();                               // S1b: row_map complete

    // ---- P1: load row, e-dots, bf16-transpose-stage into Ab[h][g]
    {
        int g = tid >> 2, c = tid & 3;
        int j = row_map[g];
        int stage = (g < M);
        int gz    = (g < KT);
        const float* ar = A + (size_t)b*PLH + (size_t)j*LH + (size_t)l*H;
        float s1 = 0.f, s2 = 0.f;
        #pragma unroll
        for (int t = 0; t < 16; ++t) {
            int o = (t*4 + c)*4;                   // h base of this float4
            float4 a  = *(const float4*)(ar + o);
            float4 v1 = *(const float4*)&u_lds[o];
            float4 v2 = *(const float4*)&u_lds[H + o];
            s1 += a.x*v1.x + a.y*v1.y + a.z*v1.z + a.w*v1.w;
            s2 += a.x*v2.x + a.y*v2.y + a.z*v2.z + a.w*v2.w;
            if (gz) {
                Ab[(o+0)*ABW2 + g] = stage ? f32_to_bf16(a.x) : (unsigned short)0;
                Ab[(o+1)*ABW2 + g] = stage ? f32_to_bf16(a.y) : (unsigned short)0;
                Ab[(o+2)*ABW2 + g] = stage ? f32_to_bf16(a.z) : (unsigned short)0;
                Ab[(o+3)*ABW2 + g] = stage ? f32_to_bf16(a.w) : (unsigned short)0;
            }
        }
        s1 += __shfl_xor(s1, 1, 4); s1 += __shfl_xor(s1, 2, 4);
        s2 += __shfl_xor(s2, 1, 4); s2 += __shfl_xor(s2, 2, 4);
        if (c == 0) {
            e1f[j] = s1;
            if (stage) e2c[g] = s2;
        }
    }
    __syncthreads();                               // S2: Ab, e1f, e2c ready

    // ---- P2: softmax (chunk-of-8) + in-register fragment redistribution
    int lane = tid & 63;
    int wv   = tid >> 6;
    int fr   = lane & 15;
    int kc   = lane >> 4;

    unsigned words[4][4];
    float myinv;
    {
        int i = tid >> 2, c = tid & 3;
        float e1v = e1f[i];
        float mx = -INFINITY;
        for (int jj = c; jj < M; jj += 4) mx = fmaxf(mx, e2c[jj]);
        mx = fmaxf(mx, __shfl_xor(mx, 1, 4));
        mx = fmaxf(mx, __shfl_xor(mx, 2, 4));
        float s0 = e1v + mx;
        float m  = fmaxf(s0, SLOPE*s0);            // leaky(e1+max e2) == row max
        float sum = 0.f;
        unsigned bw0 = bitw[i*4], bw1 = bitw[i*4+1],
                 bw2 = bitw[i*4+2], bw3 = bitw[i*4+3];
        #pragma unroll
        for (int ks = 0; ks < 4; ++ks) {
            unsigned short v[8];
            if (ks < Kn) {
                #pragma unroll
                for (int t = 0; t < 8; ++t) {
                    int jj = ks*32 + c*8 + t;
                    unsigned short wb = 0;
                    if (jj < M) {
                        int j   = row_map[jj];
                        float s = e1v + e2c[jj];
                        s = fmaxf(s, SLOPE*s);
                        float ex = __expf(s - m);
                        sum += ex;
                        unsigned sel = (j & 64) ? ((j & 32) ? bw3 : bw2)
                                                : ((j & 32) ? bw1 : bw0);
                        unsigned bit = (sel >> (j & 31)) & 1u;
                        wb = bit ? f32_to_bf16(ex) : (unsigned short)0;
                    }
                    v[t] = wb;
                }
            } else {
                #pragma unroll
                for (int t = 0; t < 8; ++t) v[t] = 0;
            }
            words[ks][0] = (unsigned)v[0] | ((unsigned)v[1] << 16);
            words[ks][1] = (unsigned)v[2] | ((unsigned)v[3] << 16);
            words[ks][2] = (unsigned)v[4] | ((unsigned)v[5] << 16);
            words[ks][3] = (unsigned)v[6] | ((unsigned)v[7] << 16);
        }
        sum += __shfl_xor(sum, 1, 4);
        sum += __shfl_xor(sum, 2, 4);
        myinv = 1.f / sum;
    }

    // fragment shuffle: lane (kc*16+fr) takes data from lane (fr*4+kc)
    bf16x8 af[4];
    int sl = ((lane & 15) << 2) | (lane >> 4);
    #pragma unroll
    for (int ks = 0; ks < 4; ++ks) {
        uint32x4 uu;
        uu.x = (unsigned)__shfl((int)words[ks][0], sl, 64);
        uu.y = (unsigned)__shfl((int)words[ks][1], sl, 64);
        uu.z = (unsigned)__shfl((int)words[ks][2], sl, 64);
        uu.w = (unsigned)__shfl((int)words[ks][3], sl, 64);
        af[ks] = __builtin_bit_cast(bf16x8, uu);
    }
    float inv4[4];
    #pragma unroll
    for (int rr = 0; rr < 4; ++rr)
        inv4[rr] = __shfl(myinv, ((lane >> 4) << 4) | (rr << 2), 64);

    // ---- P3: MFMA + sigmoid epilogue; 16 h-tiles, no barriers
    #pragma unroll 4
    for (int hq = 0; hq < 16; ++hq) {
        int hrow = hq*16 + fr;
        f32x4 acc = {0.f, 0.f, 0.f, 0.f};
        #pragma unroll
        for (int ks = 0; ks < 4; ++ks) {
            if (ks < Kn) {
                bf16x8 bf = *(const bf16x8*)&Ab[hrow*ABW2 + (ks*4 + kc)*8];
                acc = __builtin_amdgcn_mfma_f32_16x16x32_bf16(af[ks], bf, acc, 0, 0, 0);
            }
        }
        #pragma unroll
        for (int rr = 0; rr < 4; ++rr) {
            float x = acc[rr] * inv4[rr];
            float e = __expf(-x);
            out[((size_t)(b*P + wv*16 + kc*4 + rr)*L + l)*H + hrow] =
                __builtin_amdgcn_rcpf(1.f + e);
        }
    }
}

extern "C" void kernel_launch(void* const* d_in, const int* in_sizes, int n_in,
                              void* d_out, int out_size, void* d_ws, size_t ws_size,
                              hipStream_t stream) {
    const float* agents = (const float*)d_in[0];
    const float* adj    = (const float*)d_in[1];
    const void*  mask   = d_in[2];
    const float* W1     = (const float*)d_in[3];
    const float* W2     = (const float*)d_in[4];
    float* out = (float*)d_out;

    int*      flag = (int*)d_ws;
    float*    u    = (float*)d_ws + 16;
    unsigned* bits = (unsigned*)(u + 2*H);        // 1.2 MB

    prep    <<<B*P + 1, 256, 0, stream>>>(adj, (const unsigned char*)mask,
                                          W1, W2, bits, flag, u);
    gat_main<<<NBLK, 512, 0, stream>>>(agents, bits, mask, flag, u, out);
}

// Round 15
// 49.789 us; speedup vs baseline: 2.1710x; 2.1710x over previous
//
#include <hip/hip_runtime.h>
#include <math.h>

#define B  32
#define P  128
#define L  19
#define H  256
#define SLOPE 0.2f
#define PL (P*L)          /* 2432 */
#define LH (L*H)          /* 4864 */
#define PLH (P*L*H)
#define NBLK (B*L)        /* 608 */

#define WW  136           /* W  LDS row stride (u16), 272 B */
#define ABW 136           /* Ab LDS row stride (u16), 272 B */

typedef __attribute__((ext_vector_type(8))) short bf16x8;
typedef __attribute__((ext_vector_type(4))) float f32x4;

__device__ inline unsigned short f32_to_bf16(float x) {
    unsigned u = __builtin_bit_cast(unsigned, x);
    unsigned r = (u + 0x7fffu + ((u >> 16) & 1u)) >> 16;
    return (unsigned short)r;
}
__device__ inline unsigned pack_bf16x2(float f0, float f1) {
    return (unsigned)f32_to_bf16(f0) | ((unsigned)f32_to_bf16(f1) << 16);
}

// ---------------------------------------------------------------------------
// prep: blocks [0, B*P): pack adj>0 into bits[b][l][i][jw] (coalesced reads).
//       block B*P: sniff mask layout + compute u1/u2.
// ---------------------------------------------------------------------------
__global__ __launch_bounds__(256) void prep(
    const float* __restrict__ adj,
    const unsigned char* __restrict__ m,
    const float* __restrict__ W1,
    const float* __restrict__ W2,
    unsigned* __restrict__ bits,
    int* __restrict__ flag,
    float* __restrict__ u)
{
    int blk = blockIdx.x;
    if (blk < B*P) {
        __shared__ unsigned char f[PL];
        int b = blk >> 7, i = blk & 127;
        const float4* row = (const float4*)(adj + (size_t)blk * PL);
        for (int q = threadIdx.x; q < PL/4; q += 256) {
            float4 v = row[q];
            f[q*4]   = v.x > 0.f;
            f[q*4+1] = v.y > 0.f;
            f[q*4+2] = v.z > 0.f;
            f[q*4+3] = v.w > 0.f;
        }
        __syncthreads();
        int t = threadIdx.x;
        if (t < 76) {
            int l = t >> 2, jw = t & 3;
            unsigned wv = 0;
            #pragma unroll
            for (int k = 0; k < 32; ++k)
                wv |= (unsigned)f[(jw*32 + k)*L + l] << k;
            bits[(((size_t)b*L + l)*P + i)*4 + jw] = wv;
        }
    } else {
        __shared__ int s;
        if (threadIdx.x == 0) s = 0;
        __syncthreads();
        int acc = 0;
        for (int k = threadIdx.x; k < 1024; k += 256)
            acc |= m[4*k+1] | m[4*k+2] | m[4*k+3];
        if (acc) atomicOr(&s, 1);
        __syncthreads();
        if (threadIdx.x == 0) flag[0] = s;   // 1 => byte mask, 0 => int32 mask
        int h = threadIdx.x;
        float s1 = 0.f, s2 = 0.f;
        for (int a = 0; a < 128; ++a) {
            float wv = W1[a*H + h];
            s1 += wv * W2[a];
            s2 += wv * W2[128 + a];
        }
        u[h]     = s1;
        u[H + h] = s2;
    }
}

// ---------------------------------------------------------------------------
// gat_main: block = (b, l), 512 threads (8 waves), 608 blocks, 3 blocks/CU.
// R10 structure (best measured: 49.4 us total). Verified-plateau notes:
//  - 4 blocks/CU via LDS shrink: neutral (R12) — occupancy exonerated.
//  - quarter staging / fewer barriers: -18% (R13).
//  - forced 8 waves/EU: -14% (R11, VGPR squeeze 40->32).
//  - single-pass fused staging: -119% (R14, scalar ds_write + WRITE 2x).
//  P0: ballot-compact unmasked j; bitmask + u -> LDS.
//  P1: e-compute e1/e2 for all 128 j (4 thr/row, coalesced float4).
//  P2: joff pad (dup of last; W=0 col kills it), e2c gather, jreg hoist.
//  P3: stage_load(0) issued, then softmax (closed-form row max via monotone
//      leaky; 1/sum deferred to epilogue by linearity; adjacency bit test).
//  P4: MFMA loop, double-buffered Ab; Ab1 aliases the dead W region (W
//      consumed into af VGPRs first). Per eighth: {stage_load(qh+1) ->
//      MFMA(qh)+sigmoid -> stage_write(qh+1) -> barrier} (T14 split).
// ---------------------------------------------------------------------------
__global__ __launch_bounds__(512, 6) void gat_main(
    const float* __restrict__ A,
    const unsigned* __restrict__ bits,
    const void*  __restrict__ maskp,
    const int*   __restrict__ flagp,
    const float* __restrict__ u,
    float* __restrict__ out)
{
    __shared__ __align__(16) unsigned short W[P*WW];   // 34816 B [i][jj]; first
                                                       // 8704 B realiased as Ab1
    __shared__ __align__(16) unsigned short Ab0[32*ABW]; // 8704 B [h_loc][jj]
    __shared__ unsigned bitw[P*4];              // 2048 B
    __shared__ __align__(16) float u_lds[2*H];  // 2048 B
    __shared__ float e2f[P];
    __shared__ float e2c[P];
    __shared__ float e1s[P];
    __shared__ float invs[P];
    __shared__ int   joff[P];
    __shared__ int   cnt[2];

    unsigned short* Ab1 = (unsigned short*)W;   // alias: W dead after af load

    // XCD swizzle: same-b blocks land on one XCD (agents[b] ~2.4MB in L2)
    int w   = blockIdx.x;
    int xcd = w & 7;
    int q   = w >> 3;            // 0..75
    int l   = q % 19;
    int bg  = q / 19;            // 0..3
    int b   = bg*8 + xcd;
    int tid = threadIdx.x;

    // ---- P0
    int flag = flagp[0];
    int keep = 0;
    if (tid < P) {
        int mv = flag ? (((const unsigned char*)maskp)[b*P + tid] != 0)
                      : (((const int*)maskp)[b*P + tid] != 0);
        keep = !mv;
    }
    unsigned long long bal = __ballot(keep);
    if (tid == 0)  cnt[0] = (int)__popcll(bal);
    if (tid == 64) cnt[1] = (int)__popcll(bal);
    bitw[tid]  = bits[(((size_t)b*L + l)*P)*4 + tid];
    u_lds[tid] = u[tid];
    __syncthreads();                               // S1
    int M   = cnt[0] + cnt[1];
    int Kn  = (M + 31) >> 5;
    int Kn4 = Kn * 4;
    if (keep) {
        int lane = tid & 63;
        int pos  = (int)__popcll(bal & ((1ull << lane) - 1ull));
        if (tid >= 64) pos += cnt[0];
        joff[pos] = tid;
    }

    // ---- P1: e-compute (4 threads per row; 16 float4 each; width-4 reduce)
    {
        int j = tid >> 2, c = tid & 3;
        const float* ar = A + (size_t)b*PLH + (size_t)j*LH + (size_t)l*H;
        float s1 = 0.f, s2 = 0.f;
        #pragma unroll
        for (int t = 0; t < 16; ++t) {
            int o = (t*4 + c)*4;
            float4 a  = *(const float4*)(ar + o);
            float4 v1 = *(const float4*)&u_lds[o];
            float4 v2 = *(const float4*)&u_lds[H + o];
            s1 += a.x*v1.x + a.y*v1.y + a.z*v1.z + a.w*v1.w;
            s2 += a.x*v2.x + a.y*v2.y + a.z*v2.z + a.w*v2.w;
        }
        s1 += __shfl_xor(s1, 1, 4); s1 += __shfl_xor(s1, 2, 4);
        s2 += __shfl_xor(s2, 1, 4); s2 += __shfl_xor(s2, 2, 4);
        if (c == 0) { e1s[j] = s1; e2f[j] = s2; }
    }
    __syncthreads();                               // S2

    // ---- P2: pad joff, gather e2c
    if (tid < P) {
        int jsrc = (tid < M) ? joff[tid] : joff[M-1];
        if (tid >= M) joff[tid] = jsrc;
        e2c[tid] = e2f[jsrc];
    }
    __syncthreads();                               // S3

    // ---- staging helpers (T14: load early -> regs, pack+write late)
    int h_s = tid & 31;
    int jq  = tid >> 5;                            // 0..15 chunk of 8 jj
    int sw  = ((h_s >> 3) & 3) << 1;
    const float* abase = A + (size_t)b*PLH + (size_t)l*H + h_s;
    int   jreg[8];
    float rg[8];
    if (jq < Kn4) {
        #pragma unroll
        for (int t = 0; t < 8; ++t) jreg[t] = joff[jq*8 + t];
    }

    auto stage_load = [&](int qh) {
        if (jq < Kn4) {
            #pragma unroll
            for (int t = 0; t < 8; ++t)
                rg[t] = abase[(size_t)jreg[t]*LH + qh*32];
        }
    };
    auto stage_write = [&](unsigned short* ab) {
        if (jq < Kn4) {
            unsigned p0 = pack_bf16x2(rg[0], rg[1]);
            unsigned p1 = pack_bf16x2(rg[2], rg[3]);
            unsigned p2 = pack_bf16x2(rg[4], rg[5]);
            unsigned p3 = pack_bf16x2(rg[6], rg[7]);
            *(uint4*)&ab[h_s*ABW + (jq ^ sw)*8] = make_uint4(p0, p1, p2, p3);
        }
    };

    stage_load(0);    // in flight during softmax

    // ---- P3: softmax; thread (i = tid>>2, jl = tid&3), stride-4 over jj
    {
        int i  = tid >> 2;
        int jl = tid & 3;
        float e1v = e1s[i];
        float mx = -INFINITY;
        for (int jj = jl; jj < M; jj += 4) mx = fmaxf(mx, e2c[jj]);
        mx = fmaxf(mx, __shfl_xor(mx, 1, 4));
        mx = fmaxf(mx, __shfl_xor(mx, 2, 4));
        float s0 = e1v + mx;
        float m  = fmaxf(s0, SLOPE*s0);            // leaky(e1+max e2) == row max
        float sum = 0.f;
        for (int jj = jl; jj < Kn*32; jj += 4) {
            if (jj < M) {
                int j   = joff[jj];
                float s = e1v + e2c[jj];
                s = fmaxf(s, SLOPE*s);
                float ex = __expf(s - m);
                sum += ex;
                unsigned bit = (bitw[i*4 + (j >> 5)] >> (j & 31)) & 1u;
                W[i*WW + jj] = bit ? f32_to_bf16(ex) : (unsigned short)0;
            } else {
                W[i*WW + jj] = 0;                  // K pad
            }
        }
        sum += __shfl_xor(sum, 1, 4);
        sum += __shfl_xor(sum, 2, 4);
        if (jl == 0) invs[i] = 1.f / sum;
    }
    __syncthreads();                               // S4: W, invs complete

    // ---- consume W into VGPRs (must precede S5: Ab1 aliases W)
    int lane = tid & 63;
    int wv   = tid >> 6;          // i-tile
    int fr   = lane & 15;
    int kc   = lane >> 4;

    bf16x8 af[4];
    #pragma unroll
    for (int ks = 0; ks < 4; ++ks)
        if (ks < Kn) af[ks] = *(const bf16x8*)&W[(wv*16 + fr)*WW + ks*32 + kc*8];

    float inv4[4];
    #pragma unroll
    for (int rr = 0; rr < 4; ++rr) inv4[rr] = invs[wv*16 + kc*4 + rr];

    stage_write(Ab0);             // eighth 0 (rg from pre-softmax load)
    __syncthreads();                               // S5: Ab0 ready, W reads done

    // ---- P4: MFMA loop, dbuf {Ab0, Ab1=W-alias}, one barrier per eighth
    auto mfma_step = [&](int qh, const unsigned short* cur, unsigned short* nxt) {
        if (qh < 7) stage_load(qh + 1);            // latency hides under MFMA
        #pragma unroll
        for (int ht = 0; ht < 2; ++ht) {
            int row = ht*16 + fr;
            int swr = ((row >> 3) & 3) << 1;
            f32x4 acc = {0.f, 0.f, 0.f, 0.f};
            #pragma unroll
            for (int ks = 0; ks < 4; ++ks) {
                if (ks < Kn) {
                    bf16x8 bf = *(const bf16x8*)&cur[row*ABW + ((ks*4 + kc) ^ swr)*8];
                    acc = __builtin_amdgcn_mfma_f32_16x16x32_bf16(af[ks], bf, acc, 0, 0, 0);
                }
            }
            int hcol = qh*32 + ht*16 + fr;
            float* op = out + ((size_t)(b*P + wv*16 + kc*4)*L + l)*H + hcol;
            #pragma unroll
            for (int rr = 0; rr < 4; ++rr) {
                float x = acc[rr] * inv4[rr];
                float e = __expf(-x);
                op[(size_t)rr*LH] = __builtin_amdgcn_rcpf(1.f + e);
            }
        }
        if (qh < 7) {
            stage_write(nxt);
            __syncthreads();      // separates write(qh+1) from reads at qh+1;
                                  // prior reads of nxt ended before the
                                  // previous barrier.
        }
    };

    #pragma unroll
    for (int qp = 0; qp < 4; ++qp) {
        mfma_step(2*qp,     Ab0, Ab1);
        mfma_step(2*qp + 1, Ab1, Ab0);
    }
}

extern "C" void kernel_launch(void* const* d_in, const int* in_sizes, int n_in,
                              void* d_out, int out_size, void* d_ws, size_t ws_size,
                              hipStream_t stream) {
    const float* agents = (const float*)d_in[0];
    const float* adj    = (const float*)d_in[1];
    const void*  mask   = d_in[2];
    const float* W1     = (const float*)d_in[3];
    const float* W2     = (const float*)d_in[4];
    float* out = (float*)d_out;

    int*      flag = (int*)d_ws;
    float*    u    = (float*)d_ws + 16;
    unsigned* bits = (unsigned*)(u + 2*H);        // 1.2 MB

    prep    <<<B*P + 1, 256, 0, stream>>>(adj, (const unsigned char*)mask,
                                          W1, W2, bits, flag, u);
    gat_main<<<NBLK, 512, 0, stream>>>(agents, bits, mask, flag, u, out);
}

// Round 16
// 49.372 us; speedup vs baseline: 2.1894x; 1.0084x over previous
//
#include <hip/hip_runtime.h>
#include <math.h>

#define B  32
#define P  128
#define L  19
#define H  256
#define SLOPE 0.2f
#define PL (P*L)          /* 2432 */
#define LH (L*H)          /* 4864 */
#define PLH (P*L*H)
#define NBLK (B*L)        /* 608 */

#define WW  136           /* W  LDS row stride (u16), 272 B */
#define ABW 136           /* Ab LDS row stride (u16), 272 B */

typedef __attribute__((ext_vector_type(8))) short bf16x8;
typedef __attribute__((ext_vector_type(4))) float f32x4;

__device__ inline unsigned short f32_to_bf16(float x) {
    unsigned u = __builtin_bit_cast(unsigned, x);
    unsigned r = (u + 0x7fffu + ((u >> 16) & 1u)) >> 16;
    return (unsigned short)r;
}
__device__ inline unsigned pack_bf16x2(float f0, float f1) {
    return (unsigned)f32_to_bf16(f0) | ((unsigned)f32_to_bf16(f1) << 16);
}

// ---------------------------------------------------------------------------
// prep: blocks [0, B*P): pack adj>0 into bits[b][l][i][jw] (coalesced reads).
//       block B*P: sniff mask layout + compute u1/u2.
// ---------------------------------------------------------------------------
__global__ __launch_bounds__(256) void prep(
    const float* __restrict__ adj,
    const unsigned char* __restrict__ m,
    const float* __restrict__ W1,
    const float* __restrict__ W2,
    unsigned* __restrict__ bits,
    int* __restrict__ flag,
    float* __restrict__ u)
{
    int blk = blockIdx.x;
    if (blk < B*P) {
        __shared__ unsigned char f[PL];
        int b = blk >> 7, i = blk & 127;
        const float4* row = (const float4*)(adj + (size_t)blk * PL);
        for (int q = threadIdx.x; q < PL/4; q += 256) {
            float4 v = row[q];
            f[q*4]   = v.x > 0.f;
            f[q*4+1] = v.y > 0.f;
            f[q*4+2] = v.z > 0.f;
            f[q*4+3] = v.w > 0.f;
        }
        __syncthreads();
        int t = threadIdx.x;
        if (t < 76) {
            int l = t >> 2, jw = t & 3;
            unsigned wv = 0;
            #pragma unroll
            for (int k = 0; k < 32; ++k)
                wv |= (unsigned)f[(jw*32 + k)*L + l] << k;
            bits[(((size_t)b*L + l)*P + i)*4 + jw] = wv;
        }
    } else {
        __shared__ int s;
        if (threadIdx.x == 0) s = 0;
        __syncthreads();
        int acc = 0;
        for (int k = threadIdx.x; k < 1024; k += 256)
            acc |= m[4*k+1] | m[4*k+2] | m[4*k+3];
        if (acc) atomicOr(&s, 1);
        __syncthreads();
        if (threadIdx.x == 0) flag[0] = s;   // 1 => byte mask, 0 => int32 mask
        int h = threadIdx.x;
        float s1 = 0.f, s2 = 0.f;
        for (int a = 0; a < 128; ++a) {
            float wv = W1[a*H + h];
            s1 += wv * W2[a];
            s2 += wv * W2[128 + a];
        }
        u[h]     = s1;
        u[H + h] = s2;
    }
}

// ---------------------------------------------------------------------------
// gat_main: block = (b, l), 512 threads (8 waves), 608 blocks, 3 blocks/CU.
// R10/R15 structure (best measured: 49.4/49.8 us) + ONE lever: T5 s_setprio
// around the MFMA+epilogue cluster. Mechanism: 3 co-resident blocks/CU sit
// in different phases; boosting priority during the compute cluster lets
// MFMA-phase waves win issue arbitration over gather-phase waves.
// Verified-plateau notes (all isolated-tested, all reverted):
//  - 4 blocks/CU via LDS shrink: neutral (R12) — occupancy exonerated.
//  - quarter staging / fewer barriers: -18% (R13).
//  - forced 8 waves/EU: -14% (R11, VGPR squeeze 40->32).
//  - single-pass fused staging: -119% (R14, scalar ds_write + WRITE 2x).
// ---------------------------------------------------------------------------
__global__ __launch_bounds__(512, 6) void gat_main(
    const float* __restrict__ A,
    const unsigned* __restrict__ bits,
    const void*  __restrict__ maskp,
    const int*   __restrict__ flagp,
    const float* __restrict__ u,
    float* __restrict__ out)
{
    __shared__ __align__(16) unsigned short W[P*WW];   // 34816 B [i][jj]; first
                                                       // 8704 B realiased as Ab1
    __shared__ __align__(16) unsigned short Ab0[32*ABW]; // 8704 B [h_loc][jj]
    __shared__ unsigned bitw[P*4];              // 2048 B
    __shared__ __align__(16) float u_lds[2*H];  // 2048 B
    __shared__ float e2f[P];
    __shared__ float e2c[P];
    __shared__ float e1s[P];
    __shared__ float invs[P];
    __shared__ int   joff[P];
    __shared__ int   cnt[2];

    unsigned short* Ab1 = (unsigned short*)W;   // alias: W dead after af load

    // XCD swizzle: same-b blocks land on one XCD (agents[b] ~2.4MB in L2)
    int w   = blockIdx.x;
    int xcd = w & 7;
    int q   = w >> 3;            // 0..75
    int l   = q % 19;
    int bg  = q / 19;            // 0..3
    int b   = bg*8 + xcd;
    int tid = threadIdx.x;

    // ---- P0
    int flag = flagp[0];
    int keep = 0;
    if (tid < P) {
        int mv = flag ? (((const unsigned char*)maskp)[b*P + tid] != 0)
                      : (((const int*)maskp)[b*P + tid] != 0);
        keep = !mv;
    }
    unsigned long long bal = __ballot(keep);
    if (tid == 0)  cnt[0] = (int)__popcll(bal);
    if (tid == 64) cnt[1] = (int)__popcll(bal);
    bitw[tid]  = bits[(((size_t)b*L + l)*P)*4 + tid];
    u_lds[tid] = u[tid];
    __syncthreads();                               // S1
    int M   = cnt[0] + cnt[1];
    int Kn  = (M + 31) >> 5;
    int Kn4 = Kn * 4;
    if (keep) {
        int lane = tid & 63;
        int pos  = (int)__popcll(bal & ((1ull << lane) - 1ull));
        if (tid >= 64) pos += cnt[0];
        joff[pos] = tid;
    }

    // ---- P1: e-compute (4 threads per row; 16 float4 each; width-4 reduce)
    {
        int j = tid >> 2, c = tid & 3;
        const float* ar = A + (size_t)b*PLH + (size_t)j*LH + (size_t)l*H;
        float s1 = 0.f, s2 = 0.f;
        #pragma unroll
        for (int t = 0; t < 16; ++t) {
            int o = (t*4 + c)*4;
            float4 a  = *(const float4*)(ar + o);
            float4 v1 = *(const float4*)&u_lds[o];
            float4 v2 = *(const float4*)&u_lds[H + o];
            s1 += a.x*v1.x + a.y*v1.y + a.z*v1.z + a.w*v1.w;
            s2 += a.x*v2.x + a.y*v2.y + a.z*v2.z + a.w*v2.w;
        }
        s1 += __shfl_xor(s1, 1, 4); s1 += __shfl_xor(s1, 2, 4);
        s2 += __shfl_xor(s2, 1, 4); s2 += __shfl_xor(s2, 2, 4);
        if (c == 0) { e1s[j] = s1; e2f[j] = s2; }
    }
    __syncthreads();                               // S2

    // ---- P2: pad joff, gather e2c
    if (tid < P) {
        int jsrc = (tid < M) ? joff[tid] : joff[M-1];
        if (tid >= M) joff[tid] = jsrc;
        e2c[tid] = e2f[jsrc];
    }
    __syncthreads();                               // S3

    // ---- staging helpers (T14: load early -> regs, pack+write late)
    int h_s = tid & 31;
    int jq  = tid >> 5;                            // 0..15 chunk of 8 jj
    int sw  = ((h_s >> 3) & 3) << 1;
    const float* abase = A + (size_t)b*PLH + (size_t)l*H + h_s;
    int   jreg[8];
    float rg[8];
    if (jq < Kn4) {
        #pragma unroll
        for (int t = 0; t < 8; ++t) jreg[t] = joff[jq*8 + t];
    }

    auto stage_load = [&](int qh) {
        if (jq < Kn4) {
            #pragma unroll
            for (int t = 0; t < 8; ++t)
                rg[t] = abase[(size_t)jreg[t]*LH + qh*32];
        }
    };
    auto stage_write = [&](unsigned short* ab) {
        if (jq < Kn4) {
            unsigned p0 = pack_bf16x2(rg[0], rg[1]);
            unsigned p1 = pack_bf16x2(rg[2], rg[3]);
            unsigned p2 = pack_bf16x2(rg[4], rg[5]);
            unsigned p3 = pack_bf16x2(rg[6], rg[7]);
            *(uint4*)&ab[h_s*ABW + (jq ^ sw)*8] = make_uint4(p0, p1, p2, p3);
        }
    };

    stage_load(0);    // in flight during softmax

    // ---- P3: softmax; thread (i = tid>>2, jl = tid&3), stride-4 over jj
    {
        int i  = tid >> 2;
        int jl = tid & 3;
        float e1v = e1s[i];
        float mx = -INFINITY;
        for (int jj = jl; jj < M; jj += 4) mx = fmaxf(mx, e2c[jj]);
        mx = fmaxf(mx, __shfl_xor(mx, 1, 4));
        mx = fmaxf(mx, __shfl_xor(mx, 2, 4));
        float s0 = e1v + mx;
        float m  = fmaxf(s0, SLOPE*s0);            // leaky(e1+max e2) == row max
        float sum = 0.f;
        for (int jj = jl; jj < Kn*32; jj += 4) {
            if (jj < M) {
                int j   = joff[jj];
                float s = e1v + e2c[jj];
                s = fmaxf(s, SLOPE*s);
                float ex = __expf(s - m);
                sum += ex;
                unsigned bit = (bitw[i*4 + (j >> 5)] >> (j & 31)) & 1u;
                W[i*WW + jj] = bit ? f32_to_bf16(ex) : (unsigned short)0;
            } else {
                W[i*WW + jj] = 0;                  // K pad
            }
        }
        sum += __shfl_xor(sum, 1, 4);
        sum += __shfl_xor(sum, 2, 4);
        if (jl == 0) invs[i] = 1.f / sum;
    }
    __syncthreads();                               // S4: W, invs complete

    // ---- consume W into VGPRs (must precede S5: Ab1 aliases W)
    int lane = tid & 63;
    int wv   = tid >> 6;          // i-tile
    int fr   = lane & 15;
    int kc   = lane >> 4;

    bf16x8 af[4];
    #pragma unroll
    for (int ks = 0; ks < 4; ++ks)
        if (ks < Kn) af[ks] = *(const bf16x8*)&W[(wv*16 + fr)*WW + ks*32 + kc*8];

    float inv4[4];
    #pragma unroll
    for (int rr = 0; rr < 4; ++rr) inv4[rr] = invs[wv*16 + kc*4 + rr];

    stage_write(Ab0);             // eighth 0 (rg from pre-softmax load)
    __syncthreads();                               // S5: Ab0 ready, W reads done

    // ---- P4: MFMA loop, dbuf {Ab0, Ab1=W-alias}, one barrier per eighth.
    // T5: raise wave priority across the MFMA+epilogue cluster so compute-
    // phase waves win SIMD issue arbitration over gather-phase waves of the
    // other co-resident blocks.
    auto mfma_step = [&](int qh, const unsigned short* cur, unsigned short* nxt) {
        if (qh < 7) stage_load(qh + 1);            // latency hides under MFMA
        __builtin_amdgcn_s_setprio(1);
        #pragma unroll
        for (int ht = 0; ht < 2; ++ht) {
            int row = ht*16 + fr;
            int swr = ((row >> 3) & 3) << 1;
            f32x4 acc = {0.f, 0.f, 0.f, 0.f};
            #pragma unroll
            for (int ks = 0; ks < 4; ++ks) {
                if (ks < Kn) {
                    bf16x8 bf = *(const bf16x8*)&cur[row*ABW + ((ks*4 + kc) ^ swr)*8];
                    acc = __builtin_amdgcn_mfma_f32_16x16x32_bf16(af[ks], bf, acc, 0, 0, 0);
                }
            }
            int hcol = qh*32 + ht*16 + fr;
            float* op = out + ((size_t)(b*P + wv*16 + kc*4)*L + l)*H + hcol;
            #pragma unroll
            for (int rr = 0; rr < 4; ++rr) {
                float x = acc[rr] * inv4[rr];
                float e = __expf(-x);
                op[(size_t)rr*LH] = __builtin_amdgcn_rcpf(1.f + e);
            }
        }
        __builtin_amdgcn_s_setprio(0);
        if (qh < 7) {
            stage_write(nxt);
            __syncthreads();      // separates write(qh+1) from reads at qh+1;
                                  // prior reads of nxt ended before the
                                  // previous barrier.
        }
    };

    #pragma unroll
    for (int qp = 0; qp < 4; ++qp) {
        mfma_step(2*qp,     Ab0, Ab1);
        mfma_step(2*qp + 1, Ab1, Ab0);
    }
}

extern "C" void kernel_launch(void* const* d_in, const int* in_sizes, int n_in,
                              void* d_out, int out_size, void* d_ws, size_t ws_size,
                              hipStream_t stream) {
    const float* agents = (const float*)d_in[0];
    const float* adj    = (const float*)d_in[1];
    const void*  mask   = d_in[2];
    const float* W1     = (const float*)d_in[3];
    const float* W2     = (const float*)d_in[4];
    float* out = (float*)d_out;

    int*      flag = (int*)d_ws;
    float*    u    = (float*)d_ws + 16;
    unsigned* bits = (unsigned*)(u + 2*H);        // 1.2 MB

    prep    <<<B*P + 1, 256, 0, stream>>>(adj, (const unsigned char*)mask,
                                          W1, W2, bits, flag, u);
    gat_main<<<NBLK, 512, 0, stream>>>(agents, bits, mask, flag, u, out);
}